// Round 4
// baseline (129.672 us; speedup 1.0000x reference)
//
#include <hip/hip_runtime.h>

// TT Q-gather v5 — 1024-thr gather blocks (4 waves/SIMD), in-block LDS build.
//
//   v = V01[s0][s1][:]        (1 MB global table, L2-resident)
//   for k=2..5: v = v @ Gk[:,sk,:]   (bf16, 128 KB LDS built in-block
//                                     from raw fp32 G2..G5)
//   q = v . U67[s6][a7][:]    (1 MB global table, L2-resident)
//
// R3 post-mortem: v4 gather ~25us (inferred: total 89.7 - fill 42 -
// [build+gaps 22.5 from R2]). Cause: 512 thr + 128 KB LDS = 2 waves/SIMD,
// serial 4-stage dep chain + 128 KB staging prologue barely overlapped,
// 2 sequential blocks/CU. Fix: 1024-thr blocks (16 waves/CU = 4/SIMD,
// exactly 1 elem/thread, 256 blocks). Launchability REQUIRES vgpr<=128
// (16 waves x 128 = full SIMD pool) -> __launch_bounds__(1024,4) forces
// the budget; LSTAGE live set ~110 fits. LDS tables built in-block from
// fp32 cores (compile-time k loop -> no runtime pointer select), deleting
// the global Gt image + its build blocks.
//
// ws layout (ushort units):
//   V01 @ 0       : [s0][s1][s] 256*256*8   (1 MB)
//   U67 @ 524288  : [s6][a7][r] 256*256*8   (1 MB)

#define NN 256
#define RR 8
#define NR 2048   // N * R
#define U67_OFF 524288
#define GT_CORE 16384   // ushorts per core in LDS (32 KB)

__device__ __forceinline__ unsigned short f2bf_rne(float f) {
    unsigned int u = __float_as_uint(f);
    u += 0x7FFFu + ((u >> 16) & 1u);
    return (unsigned short)(u >> 16);
}

__device__ __forceinline__ uint4 pack8bf(const float* a) {
    return make_uint4(
        f2bf_rne(a[0]) | ((unsigned int)f2bf_rne(a[1]) << 16),
        f2bf_rne(a[2]) | ((unsigned int)f2bf_rne(a[3]) << 16),
        f2bf_rne(a[4]) | ((unsigned int)f2bf_rne(a[5]) << 16),
        f2bf_rne(a[6]) | ((unsigned int)f2bf_rne(a[7]) << 16));
}

// 512 blocks x 256 threads: 0..255 -> V01 row n0, 256..511 -> U67 row n6
__global__ __launch_bounds__(256) void build_tables(
    const float* __restrict__ G0, const float* __restrict__ G1,
    const float* __restrict__ G6, const float* __restrict__ G7,
    unsigned short* __restrict__ wsb) {
    const int t = threadIdx.x;
    const int bid = blockIdx.x;

    if (bid < NN) {
        // V01[n0][n1][s] = sum_r G0[n0,r] * G1[r,n1,s]
        const int n0 = bid, n1 = t;
        float acc[RR] = {0.f,0.f,0.f,0.f,0.f,0.f,0.f,0.f};
#pragma unroll
        for (int r = 0; r < RR; ++r) {
            float ar = G0[n0 * RR + r];
            const float4* p = (const float4*)(G1 + r * NR + n1 * RR);
            float4 x = p[0], y = p[1];
            acc[0] += ar * x.x; acc[1] += ar * x.y;
            acc[2] += ar * x.z; acc[3] += ar * x.w;
            acc[4] += ar * y.x; acc[5] += ar * y.y;
            acc[6] += ar * y.z; acc[7] += ar * y.w;
        }
        *(uint4*)(wsb + n0 * 2048 + n1 * 8) = pack8bf(acc);
    } else {
        // U67[n6][n7][r] = sum_s G6[r,n6,s] * G7[s,n7]
        const int n6 = bid - NN, n7 = t;
        float g7v[RR];
#pragma unroll
        for (int s = 0; s < RR; ++s) g7v[s] = G7[s * NN + n7];
        float u[RR];
#pragma unroll
        for (int r = 0; r < RR; ++r) {
            float acc = 0.f;
#pragma unroll
            for (int s = 0; s < RR; ++s)
                acc += G6[r * NR + n6 * RR + s] * g7v[s];
            u[r] = acc;
        }
        *(uint4*)(wsb + U67_OFF + n6 * 2048 + n7 * 8) = pack8bf(u);
    }
}

#define BF2F_LO(u) __uint_as_float((u) << 16)
#define BF2F_HI(u) __uint_as_float((u) & 0xFFFF0000u)

// one chain stage from LDS: v = v @ Gk[:,nidx,:]
// rows r=0..7 live at uint4 index k*2048 + r*256 + nidx
#define LSTAGE(k, nidx)                                                     \
    do {                                                                    \
        const uint4* mp = l4 + (k) * 2048 + (nidx);                         \
        uint4 r0 = mp[0],    r1 = mp[256],  r2 = mp[512],  r3 = mp[768];    \
        uint4 r4 = mp[1024], r5 = mp[1280], r6 = mp[1536], r7 = mp[1792];   \
        float nv0, nv1, nv2, nv3, nv4, nv5, nv6, nv7;                       \
        nv0  = v[0] * BF2F_LO(r0.x); nv1  = v[0] * BF2F_HI(r0.x);           \
        nv2  = v[0] * BF2F_LO(r0.y); nv3  = v[0] * BF2F_HI(r0.y);           \
        nv4  = v[0] * BF2F_LO(r0.z); nv5  = v[0] * BF2F_HI(r0.z);           \
        nv6  = v[0] * BF2F_LO(r0.w); nv7  = v[0] * BF2F_HI(r0.w);           \
        nv0 += v[1] * BF2F_LO(r1.x); nv1 += v[1] * BF2F_HI(r1.x);           \
        nv2 += v[1] * BF2F_LO(r1.y); nv3 += v[1] * BF2F_HI(r1.y);           \
        nv4 += v[1] * BF2F_LO(r1.z); nv5 += v[1] * BF2F_HI(r1.z);           \
        nv6 += v[1] * BF2F_LO(r1.w); nv7 += v[1] * BF2F_HI(r1.w);           \
        nv0 += v[2] * BF2F_LO(r2.x); nv1 += v[2] * BF2F_HI(r2.x);           \
        nv2 += v[2] * BF2F_LO(r2.y); nv3 += v[2] * BF2F_HI(r2.y);           \
        nv4 += v[2] * BF2F_LO(r2.z); nv5 += v[2] * BF2F_HI(r2.z);           \
        nv6 += v[2] * BF2F_LO(r2.w); nv7 += v[2] * BF2F_HI(r2.w);           \
        nv0 += v[3] * BF2F_LO(r3.x); nv1 += v[3] * BF2F_HI(r3.x);           \
        nv2 += v[3] * BF2F_LO(r3.y); nv3 += v[3] * BF2F_HI(r3.y);           \
        nv4 += v[3] * BF2F_LO(r3.z); nv5 += v[3] * BF2F_HI(r3.z);           \
        nv6 += v[3] * BF2F_LO(r3.w); nv7 += v[3] * BF2F_HI(r3.w);           \
        nv0 += v[4] * BF2F_LO(r4.x); nv1 += v[4] * BF2F_HI(r4.x);           \
        nv2 += v[4] * BF2F_LO(r4.y); nv3 += v[4] * BF2F_HI(r4.y);           \
        nv4 += v[4] * BF2F_LO(r4.z); nv5 += v[4] * BF2F_HI(r4.z);           \
        nv6 += v[4] * BF2F_LO(r4.w); nv7 += v[4] * BF2F_HI(r4.w);           \
        nv0 += v[5] * BF2F_LO(r5.x); nv1 += v[5] * BF2F_HI(r5.x);           \
        nv2 += v[5] * BF2F_LO(r5.y); nv3 += v[5] * BF2F_HI(r5.y);           \
        nv4 += v[5] * BF2F_LO(r5.z); nv5 += v[5] * BF2F_HI(r5.z);           \
        nv6 += v[5] * BF2F_LO(r5.w); nv7 += v[5] * BF2F_HI(r5.w);           \
        nv0 += v[6] * BF2F_LO(r6.x); nv1 += v[6] * BF2F_HI(r6.x);           \
        nv2 += v[6] * BF2F_LO(r6.y); nv3 += v[6] * BF2F_HI(r6.y);           \
        nv4 += v[6] * BF2F_LO(r6.z); nv5 += v[6] * BF2F_HI(r6.z);           \
        nv6 += v[6] * BF2F_LO(r6.w); nv7 += v[6] * BF2F_HI(r6.w);           \
        nv0 += v[7] * BF2F_LO(r7.x); nv1 += v[7] * BF2F_HI(r7.x);           \
        nv2 += v[7] * BF2F_LO(r7.y); nv3 += v[7] * BF2F_HI(r7.y);           \
        nv4 += v[7] * BF2F_LO(r7.z); nv5 += v[7] * BF2F_HI(r7.z);           \
        nv6 += v[7] * BF2F_LO(r7.w); nv7 += v[7] * BF2F_HI(r7.w);           \
        v[0] = nv0; v[1] = nv1; v[2] = nv2; v[3] = nv3;                     \
        v[4] = nv4; v[5] = nv5; v[6] = nv6; v[7] = nv7;                     \
    } while (0)

// stage one core (compile-time k) into LDS: 2 rows per thread
#define STAGE_CORE(k, Gk)                                                   \
    do {                                                                    \
        _Pragma("unroll") for (int i = 0; i < 2; ++i) {                     \
            const int rr = (i << 10) + t;     /* 0..2047 */                 \
            const int r = rr >> 8, n = rr & 255;                            \
            const float4* src = (const float4*)((Gk) + r * NR + n * RR);    \
            float4 x = src[0], y = src[1];                                  \
            float a[8] = {x.x, x.y, x.z, x.w, y.x, y.y, y.z, y.w};          \
            ((uint4*)lut)[(k) * 2048 + r * 256 + n] = pack8bf(a);           \
        }                                                                   \
    } while (0)

__global__ __launch_bounds__(1024, 4) void tt_gather(
    const unsigned short* __restrict__ wsb,
    const float* __restrict__ G2, const float* __restrict__ G3,
    const float* __restrict__ G4, const float* __restrict__ G5,
    const int* __restrict__ states, const int* __restrict__ actions,
    float* __restrict__ out, int B) {
    __shared__ unsigned short lut[4 * GT_CORE];   // 128 KB

    const int t = threadIdx.x;
    const int b = blockIdx.x * 1024 + t;
    const bool active = (b < B);
    const int base = active ? b * 7 : 0;
    const int s0 = states[base + 0] & 255;
    const int s1 = states[base + 1] & 255;
    const int s2 = states[base + 2] & 255;
    const int s3 = states[base + 3] & 255;
    const int s4 = states[base + 4] & 255;
    const int s5 = states[base + 5] & 255;
    const int s6 = states[base + 6] & 255;
    const int a7 = actions[active ? b : 0] & 255;

    // endpoint loads issued early; consumed after the barrier
    const uint4 uv = *(const uint4*)(wsb + s0 * 2048 + s1 * 8);
    const uint4 ue = *(const uint4*)(wsb + U67_OFF + s6 * 2048 + a7 * 8);

    // build the 4 middle-core bf16 tables in LDS from raw fp32 cores
    STAGE_CORE(0, G2);
    STAGE_CORE(1, G3);
    STAGE_CORE(2, G4);
    STAGE_CORE(3, G5);
    __syncthreads();

    float v[8];
    v[0] = BF2F_LO(uv.x); v[1] = BF2F_HI(uv.x);
    v[2] = BF2F_LO(uv.y); v[3] = BF2F_HI(uv.y);
    v[4] = BF2F_LO(uv.z); v[5] = BF2F_HI(uv.z);
    v[6] = BF2F_LO(uv.w); v[7] = BF2F_HI(uv.w);

    const uint4* l4 = (const uint4*)lut;
    LSTAGE(0, s2);
    LSTAGE(1, s3);
    LSTAGE(2, s4);
    LSTAGE(3, s5);

    float q = v[0] * BF2F_LO(ue.x) + v[1] * BF2F_HI(ue.x)
            + v[2] * BF2F_LO(ue.y) + v[3] * BF2F_HI(ue.y)
            + v[4] * BF2F_LO(ue.z) + v[5] * BF2F_HI(ue.z)
            + v[6] * BF2F_LO(ue.w) + v[7] * BF2F_HI(ue.w);
    if (active) out[b] = q;
}

extern "C" void kernel_launch(void* const* d_in, const int* in_sizes, int n_in,
                              void* d_out, int out_size, void* d_ws, size_t ws_size,
                              hipStream_t stream) {
    const float* G0 = (const float*)d_in[0];
    const float* G1 = (const float*)d_in[1];
    const float* G2 = (const float*)d_in[2];
    const float* G3 = (const float*)d_in[3];
    const float* G4 = (const float*)d_in[4];
    const float* G5 = (const float*)d_in[5];
    const float* G6 = (const float*)d_in[6];
    const float* G7 = (const float*)d_in[7];
    const int* states  = (const int*)d_in[8];
    const int* actions = (const int*)d_in[9];
    float* out = (float*)d_out;
    int B = in_sizes[9];

    unsigned short* wsb = (unsigned short*)d_ws;   // 2 MB used

    hipLaunchKernelGGL(build_tables, dim3(2 * NN), dim3(256), 0, stream,
                       G0, G1, G6, G7, wsb);

    hipLaunchKernelGGL(tt_gather, dim3((B + 1023) / 1024), dim3(1024), 0, stream,
                       wsb, G2, G3, G4, G5, states, actions, out, B);
}

// Round 5
// 115.443 us; speedup vs baseline: 1.1233x; 1.1233x over previous
//
#include <hip/hip_runtime.h>

// TT Q-gather v6 — 512-thr blocks (proven no-spill), 2 elements/thread for ILP.
//
//   v = V01[s0][s1][:]        (1 MB global table, L2-resident)
//   for k=2..5: v = v @ Gk[:,sk,:]   (bf16, 128 KB LDS built in-block)
//   q = v . U67[s6][a7][:]    (1 MB global table, L2-resident)
//
// R4 post-mortem: 1024-thr workgroups get pinned at 64 VGPR by hipcc
// (seen twice: v3, v5) -> row arrays spill -> 110+ MB scratch traffic =
// 53us. v4's 512-thr __launch_bounds__(512,2) config provably doesn't
// spill (256-reg budget); its weakness was latency hiding (2 waves/SIMD,
// serial 4-stage chain -> ~25us). v6 keeps the 512-thr shape and adds
// ILP: 2 independent elements per thread (b, b+512) = 4 independent
// dep chains per SIMD, and halves per-element staging (256 blocks).
// Live set ~180 regs < 256 budget. Pipe model: LDS ~4.3us (32 b128/elem
// x 12cy x ~1.8 conflict), VALU ~1.1us, endpoints ~0.9us -> ~8-13us.
//
// ws layout (ushort units):
//   V01 @ 0       : [s0][s1][s] 256*256*8   (1 MB)
//   U67 @ 524288  : [s6][a7][r] 256*256*8   (1 MB)

#define NN 256
#define RR 8
#define NR 2048   // N * R
#define U67_OFF 524288
#define GT_CORE 16384   // ushorts per core in LDS (32 KB)

__device__ __forceinline__ unsigned short f2bf_rne(float f) {
    unsigned int u = __float_as_uint(f);
    u += 0x7FFFu + ((u >> 16) & 1u);
    return (unsigned short)(u >> 16);
}

__device__ __forceinline__ uint4 pack8bf(const float* a) {
    return make_uint4(
        f2bf_rne(a[0]) | ((unsigned int)f2bf_rne(a[1]) << 16),
        f2bf_rne(a[2]) | ((unsigned int)f2bf_rne(a[3]) << 16),
        f2bf_rne(a[4]) | ((unsigned int)f2bf_rne(a[5]) << 16),
        f2bf_rne(a[6]) | ((unsigned int)f2bf_rne(a[7]) << 16));
}

// 512 blocks x 256 threads: 0..255 -> V01 row n0, 256..511 -> U67 row n6
__global__ __launch_bounds__(256) void build_tables(
    const float* __restrict__ G0, const float* __restrict__ G1,
    const float* __restrict__ G6, const float* __restrict__ G7,
    unsigned short* __restrict__ wsb) {
    const int t = threadIdx.x;
    const int bid = blockIdx.x;

    if (bid < NN) {
        // V01[n0][n1][s] = sum_r G0[n0,r] * G1[r,n1,s]
        const int n0 = bid, n1 = t;
        float acc[RR] = {0.f,0.f,0.f,0.f,0.f,0.f,0.f,0.f};
#pragma unroll
        for (int r = 0; r < RR; ++r) {
            float ar = G0[n0 * RR + r];
            const float4* p = (const float4*)(G1 + r * NR + n1 * RR);
            float4 x = p[0], y = p[1];
            acc[0] += ar * x.x; acc[1] += ar * x.y;
            acc[2] += ar * x.z; acc[3] += ar * x.w;
            acc[4] += ar * y.x; acc[5] += ar * y.y;
            acc[6] += ar * y.z; acc[7] += ar * y.w;
        }
        *(uint4*)(wsb + n0 * 2048 + n1 * 8) = pack8bf(acc);
    } else {
        // U67[n6][n7][r] = sum_s G6[r,n6,s] * G7[s,n7]
        const int n6 = bid - NN, n7 = t;
        float g7v[RR];
#pragma unroll
        for (int s = 0; s < RR; ++s) g7v[s] = G7[s * NN + n7];
        float u[RR];
#pragma unroll
        for (int r = 0; r < RR; ++r) {
            float acc = 0.f;
#pragma unroll
            for (int s = 0; s < RR; ++s)
                acc += G6[r * NR + n6 * RR + s] * g7v[s];
            u[r] = acc;
        }
        *(uint4*)(wsb + U67_OFF + n6 * 2048 + n7 * 8) = pack8bf(u);
    }
}

#define BF2F_LO(u) __uint_as_float((u) << 16)
#define BF2F_HI(u) __uint_as_float((u) & 0xFFFF0000u)

// one chain stage from LDS for chain c: vc = vc @ Gk[:,nidx,:]
// rows r=0..7 live at uint4 index k*2048 + r*256 + nidx
#define LSTAGE(vv, k, nidx)                                                 \
    do {                                                                    \
        const uint4* mp = l4 + (k) * 2048 + (nidx);                         \
        uint4 r0 = mp[0],    r1 = mp[256],  r2 = mp[512],  r3 = mp[768];    \
        uint4 r4 = mp[1024], r5 = mp[1280], r6 = mp[1536], r7 = mp[1792];   \
        float nv0, nv1, nv2, nv3, nv4, nv5, nv6, nv7;                       \
        nv0  = vv[0] * BF2F_LO(r0.x); nv1  = vv[0] * BF2F_HI(r0.x);         \
        nv2  = vv[0] * BF2F_LO(r0.y); nv3  = vv[0] * BF2F_HI(r0.y);         \
        nv4  = vv[0] * BF2F_LO(r0.z); nv5  = vv[0] * BF2F_HI(r0.z);         \
        nv6  = vv[0] * BF2F_LO(r0.w); nv7  = vv[0] * BF2F_HI(r0.w);         \
        nv0 += vv[1] * BF2F_LO(r1.x); nv1 += vv[1] * BF2F_HI(r1.x);         \
        nv2 += vv[1] * BF2F_LO(r1.y); nv3 += vv[1] * BF2F_HI(r1.y);         \
        nv4 += vv[1] * BF2F_LO(r1.z); nv5 += vv[1] * BF2F_HI(r1.z);         \
        nv6 += vv[1] * BF2F_LO(r1.w); nv7 += vv[1] * BF2F_HI(r1.w);         \
        nv0 += vv[2] * BF2F_LO(r2.x); nv1 += vv[2] * BF2F_HI(r2.x);         \
        nv2 += vv[2] * BF2F_LO(r2.y); nv3 += vv[2] * BF2F_HI(r2.y);         \
        nv4 += vv[2] * BF2F_LO(r2.z); nv5 += vv[2] * BF2F_HI(r2.z);         \
        nv6 += vv[2] * BF2F_LO(r2.w); nv7 += vv[2] * BF2F_HI(r2.w);         \
        nv0 += vv[3] * BF2F_LO(r3.x); nv1 += vv[3] * BF2F_HI(r3.x);         \
        nv2 += vv[3] * BF2F_LO(r3.y); nv3 += vv[3] * BF2F_HI(r3.y);         \
        nv4 += vv[3] * BF2F_LO(r3.z); nv5 += vv[3] * BF2F_HI(r3.z);         \
        nv6 += vv[3] * BF2F_LO(r3.w); nv7 += vv[3] * BF2F_HI(r3.w);         \
        nv0 += vv[4] * BF2F_LO(r4.x); nv1 += vv[4] * BF2F_HI(r4.x);         \
        nv2 += vv[4] * BF2F_LO(r4.y); nv3 += vv[4] * BF2F_HI(r4.y);         \
        nv4 += vv[4] * BF2F_LO(r4.z); nv5 += vv[4] * BF2F_HI(r4.z);         \
        nv6 += vv[4] * BF2F_LO(r4.w); nv7 += vv[4] * BF2F_HI(r4.w);         \
        nv0 += vv[5] * BF2F_LO(r5.x); nv1 += vv[5] * BF2F_HI(r5.x);         \
        nv2 += vv[5] * BF2F_LO(r5.y); nv3 += vv[5] * BF2F_HI(r5.y);         \
        nv4 += vv[5] * BF2F_LO(r5.z); nv5 += vv[5] * BF2F_HI(r5.z);         \
        nv6 += vv[5] * BF2F_LO(r5.w); nv7 += vv[5] * BF2F_HI(r5.w);         \
        nv0 += vv[6] * BF2F_LO(r6.x); nv1 += vv[6] * BF2F_HI(r6.x);         \
        nv2 += vv[6] * BF2F_LO(r6.y); nv3 += vv[6] * BF2F_HI(r6.y);         \
        nv4 += vv[6] * BF2F_LO(r6.z); nv5 += vv[6] * BF2F_HI(r6.z);         \
        nv6 += vv[6] * BF2F_LO(r6.w); nv7 += vv[6] * BF2F_HI(r6.w);         \
        nv0 += vv[7] * BF2F_LO(r7.x); nv1 += vv[7] * BF2F_HI(r7.x);         \
        nv2 += vv[7] * BF2F_LO(r7.y); nv3 += vv[7] * BF2F_HI(r7.y);         \
        nv4 += vv[7] * BF2F_LO(r7.z); nv5 += vv[7] * BF2F_HI(r7.z);         \
        nv6 += vv[7] * BF2F_LO(r7.w); nv7 += vv[7] * BF2F_HI(r7.w);         \
        vv[0] = nv0; vv[1] = nv1; vv[2] = nv2; vv[3] = nv3;                 \
        vv[4] = nv4; vv[5] = nv5; vv[6] = nv6; vv[7] = nv7;                 \
    } while (0)

// stage one core (compile-time k) into LDS: 4 rows per thread (512 thr)
#define STAGE_CORE(k, Gk)                                                   \
    do {                                                                    \
        _Pragma("unroll") for (int i = 0; i < 4; ++i) {                     \
            const int rr = (i << 9) + t;      /* 0..2047 */                 \
            const int r = rr >> 8, n = rr & 255;                            \
            const float4* src = (const float4*)((Gk) + r * NR + n * RR);    \
            float4 x = src[0], y = src[1];                                  \
            float a[8] = {x.x, x.y, x.z, x.w, y.x, y.y, y.z, y.w};          \
            ((uint4*)lut)[(k) * 2048 + r * 256 + n] = pack8bf(a);           \
        }                                                                   \
    } while (0)

#define UNPACK8(vv, u)                                                      \
    do {                                                                    \
        vv[0] = BF2F_LO(u.x); vv[1] = BF2F_HI(u.x);                         \
        vv[2] = BF2F_LO(u.y); vv[3] = BF2F_HI(u.y);                         \
        vv[4] = BF2F_LO(u.z); vv[5] = BF2F_HI(u.z);                         \
        vv[6] = BF2F_LO(u.w); vv[7] = BF2F_HI(u.w);                         \
    } while (0)

#define DOT8(vv, u)                                                         \
    (vv[0] * BF2F_LO(u.x) + vv[1] * BF2F_HI(u.x)                            \
   + vv[2] * BF2F_LO(u.y) + vv[3] * BF2F_HI(u.y)                            \
   + vv[4] * BF2F_LO(u.z) + vv[5] * BF2F_HI(u.z)                            \
   + vv[6] * BF2F_LO(u.w) + vv[7] * BF2F_HI(u.w))

__global__ __launch_bounds__(512, 2) void tt_gather(
    const unsigned short* __restrict__ wsb,
    const float* __restrict__ G2, const float* __restrict__ G3,
    const float* __restrict__ G4, const float* __restrict__ G5,
    const int* __restrict__ states, const int* __restrict__ actions,
    float* __restrict__ out, int B) {
    __shared__ unsigned short lut[4 * GT_CORE];   // 128 KB

    const int t = threadIdx.x;
    const int bA = blockIdx.x * 1024 + t;          // chain A element
    const int bB = bA + 512;                       // chain B element
    const bool actA = (bA < B), actB = (bB < B);
    const int baseA = actA ? bA * 7 : 0;
    const int baseB = actB ? bB * 7 : 0;

    const int a0 = states[baseA + 0] & 255, b0 = states[baseB + 0] & 255;
    const int a1 = states[baseA + 1] & 255, b1 = states[baseB + 1] & 255;
    const int a2 = states[baseA + 2] & 255, b2 = states[baseB + 2] & 255;
    const int a3 = states[baseA + 3] & 255, b3 = states[baseB + 3] & 255;
    const int a4 = states[baseA + 4] & 255, b4 = states[baseB + 4] & 255;
    const int a5 = states[baseA + 5] & 255, b5 = states[baseB + 5] & 255;
    const int a6 = states[baseA + 6] & 255, b6 = states[baseB + 6] & 255;
    const int aa = actions[actA ? bA : 0] & 255;
    const int ba = actions[actB ? bB : 0] & 255;

    // endpoint loads issued early; consumed after the barrier
    const uint4 uvA = *(const uint4*)(wsb + a0 * 2048 + a1 * 8);
    const uint4 uvB = *(const uint4*)(wsb + b0 * 2048 + b1 * 8);
    const uint4 ueA = *(const uint4*)(wsb + U67_OFF + a6 * 2048 + aa * 8);
    const uint4 ueB = *(const uint4*)(wsb + U67_OFF + b6 * 2048 + ba * 8);

    // build the 4 middle-core bf16 tables in LDS from raw fp32 cores
    STAGE_CORE(0, G2);
    STAGE_CORE(1, G3);
    STAGE_CORE(2, G4);
    STAGE_CORE(3, G5);
    __syncthreads();

    float vA[8], vB[8];
    UNPACK8(vA, uvA);
    UNPACK8(vB, uvB);

    const uint4* l4 = (const uint4*)lut;
    LSTAGE(vA, 0, a2);  LSTAGE(vB, 0, b2);
    LSTAGE(vA, 1, a3);  LSTAGE(vB, 1, b3);
    LSTAGE(vA, 2, a4);  LSTAGE(vB, 2, b4);
    LSTAGE(vA, 3, a5);  LSTAGE(vB, 3, b5);

    float qA = DOT8(vA, ueA);
    float qB = DOT8(vB, ueB);
    if (actA) out[bA] = qA;
    if (actB) out[bB] = qB;
}

extern "C" void kernel_launch(void* const* d_in, const int* in_sizes, int n_in,
                              void* d_out, int out_size, void* d_ws, size_t ws_size,
                              hipStream_t stream) {
    const float* G0 = (const float*)d_in[0];
    const float* G1 = (const float*)d_in[1];
    const float* G2 = (const float*)d_in[2];
    const float* G3 = (const float*)d_in[3];
    const float* G4 = (const float*)d_in[4];
    const float* G5 = (const float*)d_in[5];
    const float* G6 = (const float*)d_in[6];
    const float* G7 = (const float*)d_in[7];
    const int* states  = (const int*)d_in[8];
    const int* actions = (const int*)d_in[9];
    float* out = (float*)d_out;
    int B = in_sizes[9];

    unsigned short* wsb = (unsigned short*)d_ws;   // 2 MB used

    hipLaunchKernelGGL(build_tables, dim3(2 * NN), dim3(256), 0, stream,
                       G0, G1, G6, G7, wsb);

    hipLaunchKernelGGL(tt_gather, dim3((B + 1023) / 1024), dim3(512), 0, stream,
                       wsb, G2, G3, G4, G5, states, actions, out, B);
}

// Round 6
// 107.627 us; speedup vs baseline: 1.2048x; 1.0726x over previous
//
#include <hip/hip_runtime.h>

// TT Q-gather v7 — 512-thr, 2 chains/thread, row-PAIR stages to kill the spill.
//
//   v = V01[s0][s1][:]        (1 MB global table, L2-resident)
//   for k=2..5: v = v @ Gk[:,sk,:]   (bf16, 128 KB LDS built in-block)
//   q = v . U67[s6][a7][:]    (1 MB global table, L2-resident)
//
// R5 post-mortem: v6 (2 chains x 8 concurrent uint4 rows, live ~180) got
// VGPR_Count=128 and spilled anyway (60 MB scratch WRITE, VALUBusy 0.13%).
// Rule (3 data points): the allocator won't hold 8 uint4 rows/chain here.
// v7 restructures each stage into 4 row-pair steps: 2 rows/chain loaded,
// 64 FMAs, released. Peak live ~80 regs (vA/vB 16 + nA/nB 16 + 4 rows 16
// + endpoints 8 + idx ~12 + temps) — fits the 128 tier with margin.
// Loads of step i+1 / stage k+1 have index-only addresses -> compiler
// pipelines them under current FMAs; A/B interleave gives 2 indep chains.
// Pipe model (no spill): LDS ~4.3us, VALU ~1us, stage ~1us -> ~7-12us.
//
// ws layout (ushort units):
//   V01 @ 0       : [s0][s1][s] 256*256*8   (1 MB)
//   U67 @ 524288  : [s6][a7][r] 256*256*8   (1 MB)

#define NN 256
#define RR 8
#define NR 2048   // N * R
#define U67_OFF 524288
#define GT_CORE 16384   // ushorts per core in LDS (32 KB)

__device__ __forceinline__ unsigned short f2bf_rne(float f) {
    unsigned int u = __float_as_uint(f);
    u += 0x7FFFu + ((u >> 16) & 1u);
    return (unsigned short)(u >> 16);
}

__device__ __forceinline__ uint4 pack8bf(const float* a) {
    return make_uint4(
        f2bf_rne(a[0]) | ((unsigned int)f2bf_rne(a[1]) << 16),
        f2bf_rne(a[2]) | ((unsigned int)f2bf_rne(a[3]) << 16),
        f2bf_rne(a[4]) | ((unsigned int)f2bf_rne(a[5]) << 16),
        f2bf_rne(a[6]) | ((unsigned int)f2bf_rne(a[7]) << 16));
}

// 512 blocks x 256 threads: 0..255 -> V01 row n0, 256..511 -> U67 row n6
__global__ __launch_bounds__(256) void build_tables(
    const float* __restrict__ G0, const float* __restrict__ G1,
    const float* __restrict__ G6, const float* __restrict__ G7,
    unsigned short* __restrict__ wsb) {
    const int t = threadIdx.x;
    const int bid = blockIdx.x;

    if (bid < NN) {
        // V01[n0][n1][s] = sum_r G0[n0,r] * G1[r,n1,s]
        const int n0 = bid, n1 = t;
        float acc[RR] = {0.f,0.f,0.f,0.f,0.f,0.f,0.f,0.f};
#pragma unroll
        for (int r = 0; r < RR; ++r) {
            float ar = G0[n0 * RR + r];
            const float4* p = (const float4*)(G1 + r * NR + n1 * RR);
            float4 x = p[0], y = p[1];
            acc[0] += ar * x.x; acc[1] += ar * x.y;
            acc[2] += ar * x.z; acc[3] += ar * x.w;
            acc[4] += ar * y.x; acc[5] += ar * y.y;
            acc[6] += ar * y.z; acc[7] += ar * y.w;
        }
        *(uint4*)(wsb + n0 * 2048 + n1 * 8) = pack8bf(acc);
    } else {
        // U67[n6][n7][r] = sum_s G6[r,n6,s] * G7[s,n7]
        const int n6 = bid - NN, n7 = t;
        float g7v[RR];
#pragma unroll
        for (int s = 0; s < RR; ++s) g7v[s] = G7[s * NN + n7];
        float u[RR];
#pragma unroll
        for (int r = 0; r < RR; ++r) {
            float acc = 0.f;
#pragma unroll
            for (int s = 0; s < RR; ++s)
                acc += G6[r * NR + n6 * RR + s] * g7v[s];
            u[r] = acc;
        }
        *(uint4*)(wsb + U67_OFF + n6 * 2048 + n7 * 8) = pack8bf(u);
    }
}

#define BF2F_LO(u) __uint_as_float((u) << 16)
#define BF2F_HI(u) __uint_as_float((u) & 0xFFFF0000u)

// FMA two rows (2rp, 2rp+1) of an 8x8 bf16 matrix into 8 accumulators.
// ra = row 2rp, rb = row 2rp+1; weights vv[2rp], vv[2rp+1].
#define FMA_ROWPAIR(nv, vv, ra, rb, rp)                                     \
    do {                                                                    \
        const float wa = vv[2 * (rp)], wb = vv[2 * (rp) + 1];               \
        nv[0] += wa * BF2F_LO(ra.x); nv[0] += wb * BF2F_LO(rb.x);           \
        nv[1] += wa * BF2F_HI(ra.x); nv[1] += wb * BF2F_HI(rb.x);           \
        nv[2] += wa * BF2F_LO(ra.y); nv[2] += wb * BF2F_LO(rb.y);           \
        nv[3] += wa * BF2F_HI(ra.y); nv[3] += wb * BF2F_HI(rb.y);           \
        nv[4] += wa * BF2F_LO(ra.z); nv[4] += wb * BF2F_LO(rb.z);           \
        nv[5] += wa * BF2F_HI(ra.z); nv[5] += wb * BF2F_HI(rb.z);           \
        nv[6] += wa * BF2F_LO(ra.w); nv[6] += wb * BF2F_LO(rb.w);           \
        nv[7] += wa * BF2F_HI(ra.w); nv[7] += wb * BF2F_HI(rb.w);           \
    } while (0)

// one dual-chain stage: vA = vA @ Gk[:,na,:], vB = vB @ Gk[:,nb,:]
// rows r live at uint4 index k*2048 + r*256 + n; row-pair steps rp=0..3.
#define LSTAGE2(vA, vB, k, na, nb)                                          \
    do {                                                                    \
        float nA[8] = {0.f,0.f,0.f,0.f,0.f,0.f,0.f,0.f};                    \
        float nB[8] = {0.f,0.f,0.f,0.f,0.f,0.f,0.f,0.f};                    \
        const uint4* baseA = l4 + (k) * 2048 + (na);                        \
        const uint4* baseB = l4 + (k) * 2048 + (nb);                        \
        _Pragma("unroll") for (int rp = 0; rp < 4; ++rp) {                  \
            uint4 a0 = baseA[rp * 512];                                     \
            uint4 a1 = baseA[rp * 512 + 256];                               \
            uint4 b0 = baseB[rp * 512];                                     \
            uint4 b1 = baseB[rp * 512 + 256];                               \
            FMA_ROWPAIR(nA, vA, a0, a1, rp);                                \
            FMA_ROWPAIR(nB, vB, b0, b1, rp);                                \
        }                                                                   \
        _Pragma("unroll") for (int i = 0; i < 8; ++i) {                     \
            vA[i] = nA[i]; vB[i] = nB[i];                                   \
        }                                                                   \
    } while (0)

// stage one core (compile-time k) into LDS: 4 rows per thread (512 thr)
#define STAGE_CORE(k, Gk)                                                   \
    do {                                                                    \
        _Pragma("unroll") for (int i = 0; i < 4; ++i) {                     \
            const int rr = (i << 9) + t;      /* 0..2047 */                 \
            const int r = rr >> 8, n = rr & 255;                            \
            const float4* src = (const float4*)((Gk) + r * NR + n * RR);    \
            float4 x = src[0], y = src[1];                                  \
            float a[8] = {x.x, x.y, x.z, x.w, y.x, y.y, y.z, y.w};          \
            ((uint4*)lut)[(k) * 2048 + r * 256 + n] = pack8bf(a);           \
        }                                                                   \
    } while (0)

#define UNPACK8(vv, u)                                                      \
    do {                                                                    \
        vv[0] = BF2F_LO(u.x); vv[1] = BF2F_HI(u.x);                         \
        vv[2] = BF2F_LO(u.y); vv[3] = BF2F_HI(u.y);                         \
        vv[4] = BF2F_LO(u.z); vv[5] = BF2F_HI(u.z);                         \
        vv[6] = BF2F_LO(u.w); vv[7] = BF2F_HI(u.w);                         \
    } while (0)

#define DOT8(vv, u)                                                         \
    (vv[0] * BF2F_LO(u.x) + vv[1] * BF2F_HI(u.x)                            \
   + vv[2] * BF2F_LO(u.y) + vv[3] * BF2F_HI(u.y)                            \
   + vv[4] * BF2F_LO(u.z) + vv[5] * BF2F_HI(u.z)                            \
   + vv[6] * BF2F_LO(u.w) + vv[7] * BF2F_HI(u.w))

__global__ __launch_bounds__(512, 2) void tt_gather(
    const unsigned short* __restrict__ wsb,
    const float* __restrict__ G2, const float* __restrict__ G3,
    const float* __restrict__ G4, const float* __restrict__ G5,
    const int* __restrict__ states, const int* __restrict__ actions,
    float* __restrict__ out, int B) {
    __shared__ unsigned short lut[4 * GT_CORE];   // 128 KB

    const int t = threadIdx.x;
    const int bA = blockIdx.x * 1024 + t;          // chain A element
    const int bB = bA + 512;                       // chain B element
    const bool actA = (bA < B), actB = (bB < B);
    const int baseA = actA ? bA * 7 : 0;
    const int baseB = actB ? bB * 7 : 0;

    const int a0 = states[baseA + 0] & 255, b0 = states[baseB + 0] & 255;
    const int a1 = states[baseA + 1] & 255, b1 = states[baseB + 1] & 255;
    const int a2 = states[baseA + 2] & 255, b2 = states[baseB + 2] & 255;
    const int a3 = states[baseA + 3] & 255, b3 = states[baseB + 3] & 255;
    const int a4 = states[baseA + 4] & 255, b4 = states[baseB + 4] & 255;
    const int a5 = states[baseA + 5] & 255, b5 = states[baseB + 5] & 255;
    const int a6 = states[baseA + 6] & 255, b6 = states[baseB + 6] & 255;
    const int aa = actions[actA ? bA : 0] & 255;
    const int ba = actions[actB ? bB : 0] & 255;

    // endpoint loads issued early (packed: 4 uint4 = 16 regs), consumed late
    const uint4 uvA = *(const uint4*)(wsb + a0 * 2048 + a1 * 8);
    const uint4 uvB = *(const uint4*)(wsb + b0 * 2048 + b1 * 8);
    const uint4 ueA = *(const uint4*)(wsb + U67_OFF + a6 * 2048 + aa * 8);
    const uint4 ueB = *(const uint4*)(wsb + U67_OFF + b6 * 2048 + ba * 8);

    // build the 4 middle-core bf16 tables in LDS from raw fp32 cores
    STAGE_CORE(0, G2);
    STAGE_CORE(1, G3);
    STAGE_CORE(2, G4);
    STAGE_CORE(3, G5);
    __syncthreads();

    float vA[8], vB[8];
    UNPACK8(vA, uvA);
    UNPACK8(vB, uvB);

    const uint4* l4 = (const uint4*)lut;
    LSTAGE2(vA, vB, 0, a2, b2);
    LSTAGE2(vA, vB, 1, a3, b3);
    LSTAGE2(vA, vB, 2, a4, b4);
    LSTAGE2(vA, vB, 3, a5, b5);

    float qA = DOT8(vA, ueA);
    float qB = DOT8(vB, ueB);
    if (actA) out[bA] = qA;
    if (actB) out[bB] = qB;
}

extern "C" void kernel_launch(void* const* d_in, const int* in_sizes, int n_in,
                              void* d_out, int out_size, void* d_ws, size_t ws_size,
                              hipStream_t stream) {
    const float* G0 = (const float*)d_in[0];
    const float* G1 = (const float*)d_in[1];
    const float* G2 = (const float*)d_in[2];
    const float* G3 = (const float*)d_in[3];
    const float* G4 = (const float*)d_in[4];
    const float* G5 = (const float*)d_in[5];
    const float* G6 = (const float*)d_in[6];
    const float* G7 = (const float*)d_in[7];
    const int* states  = (const int*)d_in[8];
    const int* actions = (const int*)d_in[9];
    float* out = (float*)d_out;
    int B = in_sizes[9];

    unsigned short* wsb = (unsigned short*)d_ws;   // 2 MB used

    hipLaunchKernelGGL(build_tables, dim3(2 * NN), dim3(256), 0, stream,
                       G0, G1, G6, G7, wsb);

    hipLaunchKernelGGL(tt_gather, dim3((B + 1023) / 1024), dim3(512), 0, stream,
                       wsb, G2, G3, G4, G5, states, actions, out, B);
}

// Round 7
// 89.990 us; speedup vs baseline: 1.4410x; 1.1960x over previous
//
#include <hip/hip_runtime.h>

// TT Q-gather v8 — v4 shell + hand-pipelined 16-step chain (3-buffer rotation).
//
//   v = V01[s0][s1][:]        (1 MB global table, L2-resident)
//   for k=2..5: v = v @ Gk[:,sk,:]   (bf16, from 128 KB LDS, prebuilt image)
//   q = v . U67[s6][a7][:]    (1 MB global table, L2-resident)
//
// R6 post-mortem: v7's "row-pair" macro still left all stage loads
// address-independent -> scheduler hoisted them -> spill/stall persisted
// (gather ~40us inferred). v4 (straight serial chain, prebuilt-Gt copy
// staging) remains best measured: ~25us. v8 keeps v4's shell and replaces
// the chain with an explicitly software-pipelined 16-step sequence:
// 3 rotating uint4-pair buffers (X/Y/Z), depth-2 prefetch, 2 ds_read_b128
// issued + 2 retired per step. Peak live ~75 VGPR by construction.
// Also reverts v5-v7's in-block fp32->bf16 conversion (6k cy VALU/block)
// to v4's pure-copy staging of the prebuilt bf16 Gt image.
//
// ws layout (ushort units):
//   V01 @ 0       : [s0][s1][s] 256*256*8   (1 MB)
//   U67 @ 524288  : [s6][a7][r] 256*256*8   (1 MB)
//   Gt  @ 1048576 : [k][r][n][s] 4*8*256*8  (256 KB) -- LDS image, r-major

#define NN 256
#define RR 8
#define NR 2048   // N * R
#define U67_OFF 524288
#define GT_OFF  1048576
#define GT_CORE 16384   // ushorts per core (32 KB)

__device__ __forceinline__ unsigned short f2bf_rne(float f) {
    unsigned int u = __float_as_uint(f);
    u += 0x7FFFu + ((u >> 16) & 1u);
    return (unsigned short)(u >> 16);
}

__device__ __forceinline__ uint4 pack8bf(const float* a) {
    return make_uint4(
        f2bf_rne(a[0]) | ((unsigned int)f2bf_rne(a[1]) << 16),
        f2bf_rne(a[2]) | ((unsigned int)f2bf_rne(a[3]) << 16),
        f2bf_rne(a[4]) | ((unsigned int)f2bf_rne(a[5]) << 16),
        f2bf_rne(a[6]) | ((unsigned int)f2bf_rne(a[7]) << 16));
}

// 544 blocks x 256 threads:
//   0..255   -> V01 row n0
//   256..511 -> U67 row n6
//   512..543 -> transpose G2..G5 into r-major bf16 image (8 blocks/core)
__global__ __launch_bounds__(256) void build_tables(
    const float* __restrict__ G0, const float* __restrict__ G1,
    const float* __restrict__ G2, const float* __restrict__ G3,
    const float* __restrict__ G4, const float* __restrict__ G5,
    const float* __restrict__ G6, const float* __restrict__ G7,
    unsigned short* __restrict__ wsb) {
    const int t = threadIdx.x;
    const int bid = blockIdx.x;

    if (bid < NN) {
        // V01[n0][n1][s] = sum_r G0[n0,r] * G1[r,n1,s]
        const int n0 = bid, n1 = t;
        float acc[RR] = {0.f,0.f,0.f,0.f,0.f,0.f,0.f,0.f};
#pragma unroll
        for (int r = 0; r < RR; ++r) {
            float ar = G0[n0 * RR + r];
            const float4* p = (const float4*)(G1 + r * NR + n1 * RR);
            float4 x = p[0], y = p[1];
            acc[0] += ar * x.x; acc[1] += ar * x.y;
            acc[2] += ar * x.z; acc[3] += ar * x.w;
            acc[4] += ar * y.x; acc[5] += ar * y.y;
            acc[6] += ar * y.z; acc[7] += ar * y.w;
        }
        *(uint4*)(wsb + n0 * 2048 + n1 * 8) = pack8bf(acc);
    } else if (bid < 2 * NN) {
        // U67[n6][n7][r] = sum_s G6[r,n6,s] * G7[s,n7]
        const int n6 = bid - NN, n7 = t;
        float g7v[RR];
#pragma unroll
        for (int s = 0; s < RR; ++s) g7v[s] = G7[s * NN + n7];
        float u[RR];
#pragma unroll
        for (int r = 0; r < RR; ++r) {
            float acc = 0.f;
#pragma unroll
            for (int s = 0; s < RR; ++s)
                acc += G6[r * NR + n6 * RR + s] * g7v[s];
            u[r] = acc;
        }
        *(uint4*)(wsb + U67_OFF + n6 * 2048 + n7 * 8) = pack8bf(u);
    } else {
        // transpose G2..G5 -> Gt[k][r][n][s] bf16 (r-major image)
        const int q = bid - 2 * NN;        // 0..31
        const int k = q >> 3;              // 0..3 -> G2..G5
        const int chunk = q & 7;
        const float* __restrict__ Gk =
            (k == 0) ? G2 : (k == 1) ? G3 : (k == 2) ? G4 : G5;
        const int n = chunk * 32 + (t >> 3);
        const int r = t & 7;
        const float4* src = (const float4*)(Gk + r * NR + n * RR);
        float4 x = src[0], y = src[1];
        float a[8] = {x.x, x.y, x.z, x.w, y.x, y.y, y.z, y.w};
        *(uint4*)(wsb + GT_OFF + k * GT_CORE + r * 2048 + n * 8) = pack8bf(a);
    }
}

#define BF2F_LO(u) __uint_as_float((u) << 16)
#define BF2F_HI(u) __uint_as_float((u) & 0xFFFF0000u)

// load row-pair (r=2rp, 2rp+1) of core k, column-slice n into q0,q1
#define LP(q0, q1, k, nk, rp)                                               \
    do {                                                                    \
        const uint4* _p = l4 + (k) * 2048 + (nk) + (rp) * 512;              \
        q0 = _p[0];                                                         \
        q1 = _p[256];                                                       \
    } while (0)

// accumulate row-pair rp with weights v[2rp], v[2rp+1] into acc[0..7]
#define FP(q0, q1, rp)                                                      \
    do {                                                                    \
        const float wa = v[2 * (rp)], wb = v[2 * (rp) + 1];                 \
        acc[0] += wa * BF2F_LO(q0.x); acc[0] += wb * BF2F_LO(q1.x);         \
        acc[1] += wa * BF2F_HI(q0.x); acc[1] += wb * BF2F_HI(q1.x);         \
        acc[2] += wa * BF2F_LO(q0.y); acc[2] += wb * BF2F_LO(q1.y);         \
        acc[3] += wa * BF2F_HI(q0.y); acc[3] += wb * BF2F_HI(q1.y);         \
        acc[4] += wa * BF2F_LO(q0.z); acc[4] += wb * BF2F_LO(q1.z);         \
        acc[5] += wa * BF2F_HI(q0.z); acc[5] += wb * BF2F_HI(q1.z);         \
        acc[6] += wa * BF2F_LO(q0.w); acc[6] += wb * BF2F_LO(q1.w);         \
        acc[7] += wa * BF2F_HI(q0.w); acc[7] += wb * BF2F_HI(q1.w);         \
    } while (0)

#define ENDST                                                               \
    do {                                                                    \
        _Pragma("unroll") for (int i = 0; i < 8; ++i) {                     \
            v[i] = acc[i]; acc[i] = 0.f;                                    \
        }                                                                   \
    } while (0)

__global__ __launch_bounds__(512, 2) void tt_gather(
    const unsigned short* __restrict__ wsb,
    const int* __restrict__ states, const int* __restrict__ actions,
    float* __restrict__ out, int B) {
    __shared__ unsigned short lut[4 * GT_CORE];   // 128 KB

    const int t = threadIdx.x;
    const int b = blockIdx.x * 512 + t;
    const bool active = (b < B);
    const int base = active ? b * 7 : 0;
    const int s0 = states[base + 0] & 255;
    const int s1 = states[base + 1] & 255;
    const int s2 = states[base + 2] & 255;
    const int s3 = states[base + 3] & 255;
    const int s4 = states[base + 4] & 255;
    const int s5 = states[base + 5] & 255;
    const int s6 = states[base + 6] & 255;
    const int a7 = actions[active ? b : 0] & 255;

    // endpoint loads issued early; consumed after the barrier
    const uint4 uv = *(const uint4*)(wsb + s0 * 2048 + s1 * 8);
    const uint4 ue = *(const uint4*)(wsb + U67_OFF + s6 * 2048 + a7 * 8);

    // stage prebuilt bf16 Gt image: pure copy, 16 uint4 per thread
    {
        const uint4* src = (const uint4*)(wsb + GT_OFF);
        uint4* dst = (uint4*)lut;
#pragma unroll
        for (int i = 0; i < 16; ++i) dst[t + (i << 9)] = src[t + (i << 9)];
    }
    __syncthreads();

    float v[8], acc[8];
    v[0] = BF2F_LO(uv.x); v[1] = BF2F_HI(uv.x);
    v[2] = BF2F_LO(uv.y); v[3] = BF2F_HI(uv.y);
    v[4] = BF2F_LO(uv.z); v[5] = BF2F_HI(uv.z);
    v[6] = BF2F_LO(uv.w); v[7] = BF2F_HI(uv.w);
#pragma unroll
    for (int i = 0; i < 8; ++i) acc[i] = 0.f;

    const uint4* l4 = (const uint4*)lut;
    uint4 X0, X1, Y0, Y1, Z0, Z1;

    // 16-step pipeline, depth-2 prefetch, 3-buffer rotation
    LP(X0, X1, 0, s2, 0);
    LP(Y0, Y1, 0, s2, 1);
    LP(Z0, Z1, 0, s2, 2);  FP(X0, X1, 0);          // s0
    LP(X0, X1, 0, s2, 3);  FP(Y0, Y1, 1);          // s1
    LP(Y0, Y1, 1, s3, 0);  FP(Z0, Z1, 2);          // s2
    LP(Z0, Z1, 1, s3, 1);  FP(X0, X1, 3);  ENDST;  // s3
    LP(X0, X1, 1, s3, 2);  FP(Y0, Y1, 0);          // s4
    LP(Y0, Y1, 1, s3, 3);  FP(Z0, Z1, 1);          // s5
    LP(Z0, Z1, 2, s4, 0);  FP(X0, X1, 2);          // s6
    LP(X0, X1, 2, s4, 1);  FP(Y0, Y1, 3);  ENDST;  // s7
    LP(Y0, Y1, 2, s4, 2);  FP(Z0, Z1, 0);          // s8
    LP(Z0, Z1, 2, s4, 3);  FP(X0, X1, 1);          // s9
    LP(X0, X1, 3, s5, 0);  FP(Y0, Y1, 2);          // s10
    LP(Y0, Y1, 3, s5, 1);  FP(Z0, Z1, 3);  ENDST;  // s11
    LP(Z0, Z1, 3, s5, 2);  FP(X0, X1, 0);          // s12
    LP(X0, X1, 3, s5, 3);  FP(Y0, Y1, 1);          // s13
                           FP(Z0, Z1, 2);          // s14
                           FP(X0, X1, 3);  ENDST;  // s15

    float q = v[0] * BF2F_LO(ue.x) + v[1] * BF2F_HI(ue.x)
            + v[2] * BF2F_LO(ue.y) + v[3] * BF2F_HI(ue.y)
            + v[4] * BF2F_LO(ue.z) + v[5] * BF2F_HI(ue.z)
            + v[6] * BF2F_LO(ue.w) + v[7] * BF2F_HI(ue.w);
    if (active) out[b] = q;
}

extern "C" void kernel_launch(void* const* d_in, const int* in_sizes, int n_in,
                              void* d_out, int out_size, void* d_ws, size_t ws_size,
                              hipStream_t stream) {
    const float* G0 = (const float*)d_in[0];
    const float* G1 = (const float*)d_in[1];
    const float* G2 = (const float*)d_in[2];
    const float* G3 = (const float*)d_in[3];
    const float* G4 = (const float*)d_in[4];
    const float* G5 = (const float*)d_in[5];
    const float* G6 = (const float*)d_in[6];
    const float* G7 = (const float*)d_in[7];
    const int* states  = (const int*)d_in[8];
    const int* actions = (const int*)d_in[9];
    float* out = (float*)d_out;
    int B = in_sizes[9];

    unsigned short* wsb = (unsigned short*)d_ws;   // ~2.25 MB used

    hipLaunchKernelGGL(build_tables, dim3(2 * NN + 32), dim3(256), 0, stream,
                       G0, G1, G2, G3, G4, G5, G6, G7, wsb);

    hipLaunchKernelGGL(tt_gather, dim3((B + 511) / 512), dim3(512), 0, stream,
                       wsb, states, actions, out, B);
}